// Round 8
// baseline (3403.246 us; speedup 1.0000x reference)
//
#include <hip/hip_runtime.h>
#include <hip/hip_bf16.h>

#define B_  256
#define T_  256
#define F_  64
#define U_  512
#define NG_ 2048   // 4*U
#define BU_ (B_ * U_)

typedef __attribute__((ext_vector_type(8))) short short8;
typedef __attribute__((ext_vector_type(16))) float floatx16;
typedef __attribute__((ext_vector_type(4))) float floatx4;

__device__ __forceinline__ unsigned short f2bf(float f) {
    union { float f; unsigned int u; } v; v.f = f;
    unsigned int u = v.u;
    return (unsigned short)((u + 0x7FFFu + ((u >> 16) & 1u)) >> 16);
}

__global__ void cast_x_kernel(const float* __restrict__ x,
                              unsigned short* __restrict__ xb, int n) {
    int i = blockIdx.x * blockDim.x + threadIdx.x;
    if (i < n) xb[i] = f2bf(x[i]);
}

// Pack weights into 32x32x16 MFMA B-fragments, per unit-group (16 units -> 64
// block-local gate cols = 2 n32 tiles: [i16|f16] [g16|o16]).
__global__ void pack32_kernel(const float* __restrict__ W, const float* __restrict__ Uw,
                              unsigned short* __restrict__ dst, int KT, int KX) {
    long tid = (long)blockIdx.x * blockDim.x + threadIdx.x;
    long total = 32L * 2 * KT * 512;
    if (tid >= total) return;
    int j    = (int)(tid & 7);
    int lane = (int)((tid >> 3) & 63);
    int p512 = (int)(tid >> 9);
    int kt   = p512 % KT;
    int q    = p512 / KT;
    int nt   = q & 1;
    int ug   = q >> 1;
    int c    = nt * 32 + (lane & 31);
    int srcn = (c >> 4) * U_ + ug * 16 + (c & 15);
    int k    = kt * 16 + (lane >> 5) * 8 + j;
    float v  = (k < KX) ? W[(long)k * NG_ + srcn] : Uw[(long)(k - KX) * NG_ + srcn];
    dst[tid] = f2bf(v);
}

// LLC-coherent 16-B load, NON-atomic: batched issue, latencies overlap.
__device__ __forceinline__ short8 llc_load(const unsigned short* p) {
    short8 r;
    asm volatile("global_load_dwordx4 %0, %1, off sc0 sc1" : "=v"(r) : "v"(p));
    return r;
}
#define VMWAIT(N) asm volatile("s_waitcnt vmcnt(" #N ")" ::: "memory")
__device__ __forceinline__ void dep8(short8& x) { asm volatile("" : "+v"(x)); }

#define MFMA32(a, b, c) __builtin_amdgcn_mfma_f32_32x32x16_bf16(a, b, c, 0, 0, 0)

// Persistent 2-layer LSTM, fully barrier-free loop with wave specialization.
// 256 blocks x 256 thr = 1 block/CU. Block (mo,ug): mo = bid&7 (XCD-local
// communication), ug = bid>>3 (16 units). Waves 0,1 = layer1 (K split 2-way);
// waves 2,3 = layer2. Each wave free-runs its own t-loop, gated by per-WAVE
// flags (64 producers per mo per layer; consumer = 64 lanes x 64 flags, one
// ballot). Pair k-reduce via double-buffered LDS tiles + LDS seq counters.
// No __syncthreads and no cache-maintenance ops anywhere in the loop.
__global__ __launch_bounds__(256, 1) void lstm_persist(
    const unsigned short* __restrict__ xb,
    const unsigned short* __restrict__ P1,
    const unsigned short* __restrict__ P2,
    const float* __restrict__ b1, const float* __restrict__ b2,
    unsigned short* __restrict__ h1r, unsigned short* __restrict__ h2r,
    int* flags1, int* flags2)
{
    const int bid  = blockIdx.x;
    const int mo   = bid & 7;
    const int ug   = bid >> 3;
    const int tid  = threadIdx.x;
    const int w    = tid >> 6;
    const int lane = tid & 63;
    const int arow = lane & 31;
    const int koff = (lane >> 5) * 8;
    const int row  = mo * 32 + arow;
    const int pair = w >> 1;          // 0 = L1 (waves 0,1), 1 = L2 (waves 2,3)
    const int wv   = w & 1;
    const int pid  = ug * 2 + wv;     // producer id within mo-layer (0..63)

    int* f1 = flags1 + mo * 64;       // f1[p] = t+1 <=> wave p's slice of h1[t] ready
    int* f2 = flags2 + mo * 64;

    __shared__ float zs[2][2][2][2][32][36];  // [pair][slot][wv][nt][row][36] (72 KB)
    __shared__ int   seqs[2][2];
    __shared__ float bias_s[2][64];

    if (tid < 4) seqs[tid >> 1][tid & 1] = 0;
    if (tid < 128) {
        int ly = tid >> 6, idx = tid & 63;
        const float* bb = ly ? b2 : b1;
        bias_s[ly][idx] = bb[(idx >> 4) * U_ + ug * 16 + (idx & 15)];
    }

    // ---- per-wave weight fragments in VGPRs (loaded once) ----
    // L1 wave wv: ktiles wv*18..wv*18+17 of 36 (kt<4 = x, else h1 units (kt-4)*16)
    // L2 wave wv: ktiles wv*32..wv*32+31 of 64 (wv0 = W2*h1[t], wv1 = U2*h2[t-1])
    short8 wf0[32], wf1[32];
    if (pair == 0) {
        const unsigned short* base = P1 + (size_t)ug * (2 * 36 * 512);
        #pragma unroll
        for (int i = 0; i < 18; ++i) {
            wf0[i] = *(const short8*)(base + ((size_t)(0 * 36 + wv * 18 + i) * 64 + lane) * 8);
            wf1[i] = *(const short8*)(base + ((size_t)(1 * 36 + wv * 18 + i) * 64 + lane) * 8);
        }
    } else {
        const unsigned short* base = P2 + (size_t)ug * (2 * 64 * 512);
        #pragma unroll
        for (int i = 0; i < 32; ++i) {
            wf0[i] = *(const short8*)(base + ((size_t)(0 * 64 + wv * 32 + i) * 64 + lane) * 8);
            wf1[i] = *(const short8*)(base + ((size_t)(1 * 64 + wv * 32 + i) * 64 + lane) * 8);
        }
    }
    __syncthreads();   // seqs/bias ready; the ONLY block barrier in the kernel

    const int er = lane & 31;                 // epilogue row (local)
    const int u0 = wv * 8 + (lane >> 5) * 4;  // epilogue unit offset (0..15)
    float c_[4] = {0.f, 0.f, 0.f, 0.f};      // cell state in registers
    unsigned short* hbase = pair ? h2r : h1r;
    int* myflag = (pair ? f2 : f1) + pid;

    for (int t = 0; t < T_; ++t) {
        // ---------------- flag wait (per-wave targets) ----------------
        {
            int tgt1, tgt2;   // on f1 / f2; <=0 means skip
            if (pair == 0) { tgt1 = t; tgt2 = (wv == 0) ? (t - 3) : 0; } // h1[t-1]; ring backpressure vs L2 reading h1[t-4]
            else           { tgt1 = (wv == 0) ? (t + 1) : 0;            // h1[t] ready
                             tgt2 = (wv == 0) ? 0 : t; }                // h2[t-1] ready
            if (tgt1 > 0 || tgt2 > 0) {
                const int* p1 = f1 + lane;
                const int* p2 = f2 + lane;
                int guard = 0;
                for (;;) {
                    bool ok = true;
                    if (tgt1 > 0) ok = ok && (__hip_atomic_load(p1, __ATOMIC_RELAXED, __HIP_MEMORY_SCOPE_AGENT) >= tgt1);
                    if (tgt2 > 0) ok = ok && (__hip_atomic_load(p2, __ATOMIC_RELAXED, __HIP_MEMORY_SCOPE_AGENT) >= tgt2);
                    if (__ballot(ok) == ~0ull) break;
                    __builtin_amdgcn_s_sleep(1);
                    if (++guard > (1 << 21)) break;   // fail visibly, never hang
                }
            }
            __atomic_signal_fence(__ATOMIC_ACQUIRE);
        }

        // ---------------- batched loads + MFMA (full K per wave) ----------------
        floatx16 acc0, acc1;
        #pragma unroll
        for (int i = 0; i < 16; ++i) { acc0[i] = 0.f; acc1[i] = 0.f; }

        if (pair == 0) {
            short8 fr[18];
            int nh = 0;
            if (wv == 0) {
                const unsigned short* xbase = xb + ((size_t)row * T_ + t) * F_;
                #pragma unroll
                for (int i = 0; i < 4; ++i) fr[i] = *(const short8*)(xbase + i * 16 + koff);
                if (t > 0) {
                    const unsigned short* hb = h1r + (size_t)((t - 1) & 3) * BU_ + (size_t)row * U_;
                    #pragma unroll
                    for (int i = 4; i < 18; ++i) fr[i] = llc_load(hb + (i - 4) * 16 + koff);
                    nh = 18;
                } else nh = 4;
            } else if (t > 0) {
                const unsigned short* hb = h1r + (size_t)((t - 1) & 3) * BU_ + (size_t)row * U_ + 224;
                #pragma unroll
                for (int i = 0; i < 18; ++i) fr[i] = llc_load(hb + i * 16 + koff);
                nh = 18;
            }
            if (nh == 18) {
                VMWAIT(0);
                #pragma unroll
                for (int i = 0; i < 18; ++i) {
                    dep8(fr[i]);
                    acc0 = MFMA32(fr[i], wf0[i], acc0);
                    acc1 = MFMA32(fr[i], wf1[i], acc1);
                }
            } else if (nh == 4) {
                VMWAIT(0);
                #pragma unroll
                for (int i = 0; i < 4; ++i) {
                    dep8(fr[i]);
                    acc0 = MFMA32(fr[i], wf0[i], acc0);
                    acc1 = MFMA32(fr[i], wf1[i], acc1);
                }
            }
        } else {
            short8 fr[32];
            bool have = false;
            if (wv == 0) {
                const unsigned short* hb = h1r + (size_t)(t & 3) * BU_ + (size_t)row * U_;
                #pragma unroll
                for (int i = 0; i < 32; ++i) fr[i] = llc_load(hb + i * 16 + koff);
                have = true;
            } else if (t > 0) {
                const unsigned short* hb = h2r + (size_t)((t - 1) & 3) * BU_ + (size_t)row * U_;
                #pragma unroll
                for (int i = 0; i < 32; ++i) fr[i] = llc_load(hb + i * 16 + koff);
                have = true;
            }
            if (have) {
                VMWAIT(0);
                #pragma unroll
                for (int i = 0; i < 32; ++i) {
                    dep8(fr[i]);
                    acc0 = MFMA32(fr[i], wf0[i], acc0);
                    acc1 = MFMA32(fr[i], wf1[i], acc1);
                }
            }
        }

        // ---------------- pair k-reduce via LDS (no barrier) ----------------
        const int slot = t & 1;
        #pragma unroll
        for (int r = 0; r < 16; ++r) {
            int rr = (r & 3) + 8 * (r >> 2) + 4 * (lane >> 5);
            zs[pair][slot][wv][0][rr][arow] = acc0[r];
            zs[pair][slot][wv][1][rr][arow] = acc1[r];
        }
        asm volatile("s_waitcnt lgkmcnt(0)" ::: "memory");
        __hip_atomic_store(&seqs[pair][wv], t + 1, __ATOMIC_RELEASE, __HIP_MEMORY_SCOPE_WORKGROUP);
        {
            int guard = 0;
            while (__hip_atomic_load(&seqs[pair][wv ^ 1], __ATOMIC_ACQUIRE, __HIP_MEMORY_SCOPE_WORKGROUP) <= t) {
                if (++guard > (1 << 24)) break;
            }
        }

        // ---------------- epilogue: z = p0+p1+bias, gates, c, h ----------------
        {
            const floatx4 i0 = *(const floatx4*)&zs[pair][slot][0][0][er][u0];
            const floatx4 f0 = *(const floatx4*)&zs[pair][slot][0][0][er][16 + u0];
            const floatx4 g0 = *(const floatx4*)&zs[pair][slot][0][1][er][u0];
            const floatx4 o0 = *(const floatx4*)&zs[pair][slot][0][1][er][16 + u0];
            const floatx4 i1 = *(const floatx4*)&zs[pair][slot][1][0][er][u0];
            const floatx4 f1v= *(const floatx4*)&zs[pair][slot][1][0][er][16 + u0];
            const floatx4 g1 = *(const floatx4*)&zs[pair][slot][1][1][er][u0];
            const floatx4 o1 = *(const floatx4*)&zs[pair][slot][1][1][er][16 + u0];
            unsigned long long hq = 0;
            #pragma unroll
            for (int j = 0; j < 4; ++j) {
                float zi = i0[j] + i1[j] + bias_s[pair][ 0 + u0 + j];
                float zf = f0[j] + f1v[j]+ bias_s[pair][16 + u0 + j];
                float zg = g0[j] + g1[j] + bias_s[pair][32 + u0 + j];
                float zo = o0[j] + o1[j] + bias_s[pair][48 + u0 + j];
                float si = 1.f / (1.f + __expf(-zi));
                float sf = 1.f / (1.f + __expf(-zf));
                float so = 1.f / (1.f + __expf(-zo));
                float gg = zg > 0.f ? zg : 0.f;
                float cn = sf * c_[j] + si * gg;
                c_[j] = cn;
                float hn = so * (cn > 0.f ? cn : 0.f);
                hq |= ((unsigned long long)f2bf(hn)) << (16 * j);
            }
            unsigned long long* hp = (unsigned long long*)
                (hbase + (size_t)(t & 3) * BU_ + (size_t)(mo * 32 + er) * U_ + ug * 16 + u0);
            __hip_atomic_store(hp, hq, __ATOMIC_RELAXED, __HIP_MEMORY_SCOPE_AGENT);
        }
        VMWAIT(0);                                  // own 8B h-store drained to LLC
        __atomic_signal_fence(__ATOMIC_RELEASE);
        __hip_atomic_store(myflag, t + 1, __ATOMIC_RELAXED, __HIP_MEMORY_SCOPE_AGENT);
    }
}

__global__ void dense_kernel(const unsigned short* __restrict__ h2,
                             const float* __restrict__ Wd,
                             const float* __restrict__ bd,
                             float* __restrict__ out) {
    int b = blockIdx.x;
    int lane = threadIdx.x;                  // 64 lanes
    const unsigned short* hp = h2 + (long)b * U_ + lane * 8;
    float sum = 0.f;
    #pragma unroll
    for (int j = 0; j < 8; ++j) {
        union { unsigned int u; float f; } v; v.u = ((unsigned int)hp[j]) << 16;
        sum += v.f * Wd[lane * 8 + j];
    }
    #pragma unroll
    for (int off = 32; off; off >>= 1) sum += __shfl_down(sum, off);
    if (lane == 0) out[b] = 1.f / (1.f + __expf(-(sum + bd[0])));
}

extern "C" void kernel_launch(void* const* d_in, const int* in_sizes, int n_in,
                              void* d_out, int out_size, void* d_ws, size_t ws_size,
                              hipStream_t stream) {
    const float* x  = (const float*)d_in[0];
    const float* W1 = (const float*)d_in[1];
    const float* U1 = (const float*)d_in[2];
    const float* b1 = (const float*)d_in[3];
    const float* W2 = (const float*)d_in[4];
    const float* U2 = (const float*)d_in[5];
    const float* b2 = (const float*)d_in[6];
    const float* Wd = (const float*)d_in[7];
    const float* bd = (const float*)d_in[8];
    float* out = (float*)d_out;

    char* ws = (char*)d_ws;
    size_t off = 0;
    unsigned short* xb  = (unsigned short*)(ws + off); off += (size_t)B_ * T_ * F_ * 2;      // 8.39 MB
    unsigned short* P1  = (unsigned short*)(ws + off); off += (size_t)32 * 2 * 36 * 512 * 2; // 2.36 MB
    unsigned short* P2  = (unsigned short*)(ws + off); off += (size_t)32 * 2 * 64 * 512 * 2; // 4.19 MB
    unsigned short* h1r = (unsigned short*)(ws + off); off += (size_t)4 * BU_ * 2;           // 1 MB
    unsigned short* h2r = (unsigned short*)(ws + off); off += (size_t)4 * BU_ * 2;           // 1 MB
    int* flags1 = (int*)(ws + off); off += (size_t)8 * 64 * 4;   // per-wave flags
    int* flags2 = (int*)(ws + off); off += (size_t)8 * 64 * 4;

    hipMemsetAsync(flags1, 0, (size_t)8 * 64 * 4 * 2, stream);

    int n = B_ * T_ * F_;
    cast_x_kernel<<<(n + 255) / 256, 256, 0, stream>>>(x, xb, n);
    {
        long tot1 = 32L * 2 * 36 * 512;
        pack32_kernel<<<(int)((tot1 + 255) / 256), 256, 0, stream>>>(W1, U1, P1, 36, 64);
        long tot2 = 32L * 2 * 64 * 512;
        pack32_kernel<<<(int)((tot2 + 255) / 256), 256, 0, stream>>>(W2, U2, P2, 64, 512);
    }

    // 256 blocks = 1 block/CU: co-residency guaranteed, plain launch.
    lstm_persist<<<256, 256, 0, stream>>>(xb, P1, P2, b1, b2, h1r, h2r, flags1, flags2);

    dense_kernel<<<B_, 64, 0, stream>>>(h2r + (size_t)((T_ - 1) & 3) * BU_,
                                        Wd, bd, out);
}